// Round 3
// baseline (238.551 us; speedup 1.0000x reference)
//
#include <hip/hip_runtime.h>
#include <stdint.h>

#define Bn  8
#define LQn 2048
#define LKn 2048
#define Dn  512
#define NKS 33          // 32 d-slices of 16 + 1 mask slice
#define NT  8           // 2048 keys / 256 per iter

using f32x4  = __attribute__((ext_vector_type(4)))  float;
using f32x16 = __attribute__((ext_vector_type(16))) float;
using bf16x8 = __attribute__((ext_vector_type(8)))  __bf16;
using u16x8  = __attribute__((ext_vector_type(8)))  unsigned short;

// ws layout
#define WS_MASK_OFF 256
#define WS_KP_OFF   (WS_MASK_OFF + Bn*LKn*4)                       // K packed: [B][64 kg][33 ks][64 lane][8] bf16
#define KP_BYTES    ((size_t)Bn*64*NKS*1024)
#define WS_VP_OFF   (WS_KP_OFF + KP_BYTES)                         // V packed: [B][128 kslice][16 dg][64 lane][8] bf16
#define VP_BYTES    ((size_t)Bn*128*16*1024)
#define WS_REQ      ((size_t)WS_VP_OFF + VP_BYTES)

union BFU { __bf16 h; unsigned short u; };
static __device__ __forceinline__ unsigned short f2bfu(float x) { BFU t; t.h = (__bf16)x; return t.u; }

// ---- mask dtype detect + additive bias build: maskadd = masked ? -1e30/scale : 0 ----
__global__ void mask_prep_kernel(const void* __restrict__ mraw, const float* __restrict__ scalep,
                                 float* __restrict__ maskadd) {
  __shared__ int sBig, sOff;
  const int tid = threadIdx.x;
  if (tid == 0) { sBig = 0; sOff = 0; }
  __syncthreads();
  const unsigned char* mb = (const unsigned char*)mraw;
  int big = 0, off = 0;
  for (int i = tid; i < Bn*LKn; i += blockDim.x) {
    unsigned char v = mb[i];
    big |= (v > 1) ? 1 : 0;
    off |= (((i & 3) != 0) && v != 0) ? 1 : 0;
  }
  if (big) atomicOr(&sBig, 1);
  if (off) atomicOr(&sOff, 1);
  __syncthreads();
  const int f = sBig ? 2 : (sOff ? 1 : 0);
  const float bias = -1e30f / scalep[0];
  for (int i = tid; i < Bn*LKn; i += blockDim.x) {
    bool m;
    if (f == 2)      m = ((const float*)mraw)[i] != 0.0f;
    else if (f == 1) m = mb[i] != 0;
    else             m = ((const int*)mraw)[i] != 0;
    maskadd[i] = m ? bias : 0.0f;
  }
}

// ---- K fp32 [B][LK][D] -> Kp frag-packed bf16, mask folded as d-slice 32 ----
__global__ void conv_kp_kernel(const float* __restrict__ k, const float* __restrict__ maskadd,
                               unsigned short* __restrict__ kp) {
  const int gid = blockIdx.x * 256 + threadIdx.x;
  const int frag = gid >> 6, lane = gid & 63;
  const int b = frag / (64*NKS);
  const int rem = frag - b*(64*NKS);
  const int kg = rem / NKS;
  const int ks = rem - kg*NKS;
  const int key = kg*32 + (lane & 31);
  const int hi = lane >> 5;
  u16x8 o;
  if (ks < 32) {
    const float* src = k + ((size_t)(b*LKn) + key)*Dn + ks*16 + hi*8;
    const f32x4 a = *(const f32x4*)src;
    const f32x4 c = *(const f32x4*)(src + 4);
#pragma unroll
    for (int j = 0; j < 4; ++j) { o[j] = f2bfu(a[j]); o[j+4] = f2bfu(c[j]); }
  } else {
#pragma unroll
    for (int j = 0; j < 8; ++j) o[j] = 0;
    if (hi == 0) o[0] = f2bfu(maskadd[b*LKn + key]);
  }
  *(u16x8*)(kp + (size_t)frag*512 + lane*8) = o;
}

// ---- V fp32 [B][LK][D] -> Vp frag-packed bf16: [B][kslice][dg][lane][8] ----
__global__ void conv_vp_kernel(const float* __restrict__ v, unsigned short* __restrict__ vp) {
  __shared__ float vt[16*512];
  const int b = blockIdx.y, kslice = blockIdx.x;
  const float* src = v + ((size_t)(b*LKn) + kslice*16)*Dn;
#pragma unroll
  for (int p = 0; p < 8; ++p) {
    const int idx = p*256 + threadIdx.x;                 // f32x4 index, 2048 total
    *(f32x4*)&vt[idx*4] = *(const f32x4*)(src + (size_t)idx*4);
  }
  __syncthreads();
  unsigned short* dst = vp + ((size_t)(b*128 + kslice)*16)*512;
#pragma unroll
  for (int p = 0; p < 4; ++p) {
    const int slot = p*256 + threadIdx.x;                // 1024 lane-slots
    const int dg = slot >> 6, lane = slot & 63;
    const int d = dg*32 + (lane & 31);
    const int k0 = (lane >> 5)*8;
    u16x8 o;
#pragma unroll
    for (int j = 0; j < 8; ++j) o[j] = f2bfu(vt[(k0+j)*512 + d]);
    *(u16x8*)(dst + (size_t)dg*512 + lane*8) = o;
  }
}

// ---- flash attention: 32 q-rows/block, 8 waves x 32 keys/iter, reg-streamed K/V ----
__launch_bounds__(512, 2)
__global__ void attn_kernel(const float* __restrict__ q, const unsigned short* __restrict__ kp,
                            const unsigned short* __restrict__ vp,
                            const float* __restrict__ ratio, const float* __restrict__ scalep,
                            float* __restrict__ out) {
  __shared__ __align__(16) unsigned short Pl[16*512];   // 16 KiB: [ks(16)][q(32)][h(2)][8] bf16
  __shared__ float redm[8][32];
  __shared__ float reds[8][32];

  const int tid = threadIdx.x;
  const int w = tid >> 6, lane = tid & 63;
  const int qc = lane & 31, hi = lane >> 5;
  const int b = blockIdx.x & 7, qtile = blockIdx.x >> 3;   // XCD-affine batches
  const int qbase = qtile * 32;
  const float c2 = scalep[0] * ratio[b] * 1.4426950408889634f;

  // Q fragments in registers (B-operand: col=q, k=hi*8+j), plus mask-dim slice
  bf16x8 qf[NKS];
  {
    const float* qrow = q + ((size_t)(b*LQn) + qbase + qc)*Dn + hi*8;
#pragma unroll
    for (int ks = 0; ks < 32; ++ks) {
      const f32x4 a = *(const f32x4*)(qrow + ks*16);
      const f32x4 c = *(const f32x4*)(qrow + ks*16 + 4);
      bf16x8 f;
#pragma unroll
      for (int j = 0; j < 4; ++j) { f[j] = (__bf16)a[j]; f[j+4] = (__bf16)c[j]; }
      qf[ks] = f;
    }
    bf16x8 f;
#pragma unroll
    for (int j = 0; j < 8; ++j) f[j] = (__bf16)0.0f;
    if (hi == 0) f[0] = (__bf16)1.0f;
    qf[32] = f;
  }

  f32x16 o0, o1;
#pragma unroll
  for (int r = 0; r < 16; ++r) { o0[r] = 0.f; o1[r] = 0.f; }
  float m_old = -3.0e38f, lacc = 0.f;

  const char* kpB = (const char*)kp + (size_t)b*(64*NKS)*1024;
  const char* vpB = (const char*)vp + (size_t)b*2048*1024;
  const int loff = lane*16;

  for (int t = 0; t < NT; ++t) {
    // ---- QK^T swapped: S[key][q] = mfma(A=Kfrag, B=Qfrag); wave owns keys (t*8+w)*32.. ----
    const char* kf = kpB + (size_t)(t*8 + w)*NKS*1024 + loff;
    f32x16 S;
#pragma unroll
    for (int r = 0; r < 16; ++r) S[r] = 0.f;
    __builtin_amdgcn_s_setprio(1);
#pragma unroll
    for (int ks = 0; ks < NKS; ++ks) {
      const bf16x8 kk = *(const bf16x8*)(kf + ks*1024);
      S = __builtin_amdgcn_mfma_f32_32x32x16_bf16(kk, qf[ks], S, 0, 0, 0);
    }
    __builtin_amdgcn_s_setprio(0);

    // scale (mask already inside S); per-q max: 15 in-lane fmax + 1 shfl
    float sl[16];
#pragma unroll
    for (int r = 0; r < 16; ++r) sl[r] = S[r]*c2;
    float vmax = sl[0];
#pragma unroll
    for (int r = 1; r < 16; ++r) vmax = fmaxf(vmax, sl[r]);
    vmax = fmaxf(vmax, __shfl_xor(vmax, 32));
    if (lane < 32) redm[w][lane] = vmax;
    __syncthreads();                                   // barrier A: redm ready, P readers done

    float mt = redm[0][qc];
#pragma unroll
    for (int w2 = 1; w2 < 8; ++w2) mt = fmaxf(mt, redm[w2][qc]);
    const float m_new = fmaxf(m_old, mt);
    const float fac = exp2f(m_old - m_new);
    m_old = m_new;

    // P = exp2(sl - m), pack to bf16 pairs, write 4x ds_write_b64
    float ps = 0.f;
    unsigned int pw[8];
#pragma unroll
    for (int r = 0; r < 16; r += 2) {
      const float p0 = exp2f(sl[r]   - m_new);
      const float p1 = exp2f(sl[r+1] - m_new);
      ps += p0 + p1;
      pw[r >> 1] = (unsigned int)f2bfu(p0) | ((unsigned int)f2bfu(p1) << 16);
    }
    {
      char* pb = (char*)Pl + (w*2)*1024 + qc*32 + hi*8;
      *(unsigned long long*)(pb)        = (unsigned long long)pw[0] | ((unsigned long long)pw[1] << 32);
      *(unsigned long long*)(pb + 16)   = (unsigned long long)pw[2] | ((unsigned long long)pw[3] << 32);
      *(unsigned long long*)(pb + 1024) = (unsigned long long)pw[4] | ((unsigned long long)pw[5] << 32);
      *(unsigned long long*)(pb + 1040) = (unsigned long long)pw[6] | ((unsigned long long)pw[7] << 32);
    }
    ps += __shfl_xor(ps, 32);
    if (lane < 32) reds[w][lane] = ps;
    __syncthreads();                                   // barrier B: P + reds ready

    float lsum = reds[0][qc];
#pragma unroll
    for (int w2 = 1; w2 < 8; ++w2) lsum += reds[w2][qc];
    lacc = lacc*fac + lsum;
#pragma unroll
    for (int r = 0; r < 16; ++r) { o0[r] *= fac; o1[r] *= fac; }

    // ---- PV: O^T[d][q] += V^T-frag x P-frag; wave owns d-cols w*64..w*64+63 ----
    const char* vf = vpB + ((size_t)(t*16)*16 + w*2)*1024 + loff;
    const char* pr = (const char*)Pl + qc*32 + hi*16;
    __builtin_amdgcn_s_setprio(1);
#pragma unroll
    for (int ks = 0; ks < 16; ++ks) {
      const bf16x8 pf = *(const bf16x8*)(pr + ks*1024);
      const bf16x8 va = *(const bf16x8*)(vf + (size_t)ks*16*1024);
      const bf16x8 vb = *(const bf16x8*)(vf + (size_t)ks*16*1024 + 1024);
      o0 = __builtin_amdgcn_mfma_f32_32x32x16_bf16(va, pf, o0, 0, 0, 0);
      o1 = __builtin_amdgcn_mfma_f32_32x32x16_bf16(vb, pf, o1, 0, 0, 0);
    }
    __builtin_amdgcn_s_setprio(0);
  }

  // epilogue: out[q][d] = O^T[d][q] / l   (C row = (r&3)+8*(r>>2)+4*hi)
  const float linv = 1.0f / lacc;
  float* ob = out + ((size_t)(b*LQn) + qbase + qc)*Dn;
#pragma unroll
  for (int i = 0; i < 2; ++i) {
    const int dgb = (w*2 + i)*32;
#pragma unroll
    for (int rq = 0; rq < 4; ++rq) {
      f32x4 ov;
#pragma unroll
      for (int c = 0; c < 4; ++c) ov[c] = (i ? o1[rq*4 + c] : o0[rq*4 + c]) * linv;
      *(f32x4*)(ob + dgb + rq*8 + hi*4) = ov;
    }
  }
}

extern "C" void kernel_launch(void* const* d_in, const int* in_sizes, int n_in,
                              void* d_out, int out_size, void* d_ws, size_t ws_size,
                              hipStream_t stream) {
  const float* q      = (const float*)d_in[0];
  const float* k      = (const float*)d_in[1];
  const float* v      = (const float*)d_in[2];
  const float* ratio  = (const float*)d_in[3];
  const float* scalep = (const float*)d_in[4];
  const void*  mask   = d_in[5];
  float* out = (float*)d_out;
  char* ws = (char*)d_ws;

  if (ws_size < WS_REQ) return;

  float* maskadd      = (float*)(ws + WS_MASK_OFF);
  unsigned short* kpk = (unsigned short*)(ws + WS_KP_OFF);
  unsigned short* vpk = (unsigned short*)(ws + WS_VP_OFF);

  hipLaunchKernelGGL(mask_prep_kernel, dim3(1), dim3(1024), 0, stream, mask, scalep, maskadd);
  hipLaunchKernelGGL(conv_kp_kernel, dim3(Bn*64*NKS*64/256), dim3(256), 0, stream, k, maskadd, kpk);
  hipLaunchKernelGGL(conv_vp_kernel, dim3(128, Bn), dim3(256), 0, stream, v, vpk);
  hipLaunchKernelGGL(attn_kernel, dim3(Bn*(LQn/32)), dim3(512), 0, stream,
                     q, kpk, vpk, ratio, scalep, out);
}

// Round 4
// 203.162 us; speedup vs baseline: 1.1742x; 1.1742x over previous
//
#include <hip/hip_runtime.h>
#include <stdint.h>

#define Bn  8
#define LQn 2048
#define LKn 2048
#define Dn  512
#define NKS 32          // 32 d-slices of 16
#define NT  8           // 2048 keys / 256 per iter

using f32x4  = __attribute__((ext_vector_type(4)))  float;
using f32x16 = __attribute__((ext_vector_type(16))) float;
using bf16x8 = __attribute__((ext_vector_type(8)))  __bf16;
using u16x8  = __attribute__((ext_vector_type(8)))  unsigned short;

// ws layout
#define WS_MASK_OFF 256
#define WS_KP_OFF   (WS_MASK_OFF + Bn*LKn*4)                 // K pack: [B][64 kg][32 ks][64 lane][8] bf16
#define KP_BYTES    ((size_t)Bn*64*NKS*1024)
#define WS_VP_OFF   (WS_KP_OFF + KP_BYTES)                   // V pack: [B][128 kslice][16 dg][64 lane][8] bf16
#define VP_BYTES    ((size_t)Bn*128*16*1024)
#define WS_REQ      ((size_t)WS_VP_OFF + VP_BYTES)

union BFU { __bf16 h; unsigned short u; };
static __device__ __forceinline__ unsigned short f2bfu(float x) { BFU t; t.h = (__bf16)x; return t.u; }

// ---- mask dtype detect + additive bias build: maskadd = masked ? -1e30 : 0 ----
__global__ void mask_prep_kernel(const void* __restrict__ mraw, float* __restrict__ maskadd) {
  __shared__ int sBig, sOff;
  const int tid = threadIdx.x;
  if (tid == 0) { sBig = 0; sOff = 0; }
  __syncthreads();
  const unsigned char* mb = (const unsigned char*)mraw;
  int big = 0, off = 0;
  for (int i = tid; i < Bn*LKn; i += blockDim.x) {
    unsigned char v = mb[i];
    big |= (v > 1) ? 1 : 0;
    off |= (((i & 3) != 0) && v != 0) ? 1 : 0;
  }
  if (big) atomicOr(&sBig, 1);
  if (off) atomicOr(&sOff, 1);
  __syncthreads();
  const int f = sBig ? 2 : (sOff ? 1 : 0);
  for (int i = tid; i < Bn*LKn; i += blockDim.x) {
    bool m;
    if (f == 2)      m = ((const float*)mraw)[i] != 0.0f;
    else if (f == 1) m = mb[i] != 0;
    else             m = ((const int*)mraw)[i] != 0;
    maskadd[i] = m ? -1e30f : 0.0f;
  }
}

// ---- K fp32 [B][LK][D] -> Kp frag-packed bf16 ----
__global__ void conv_kp_kernel(const float* __restrict__ k, unsigned short* __restrict__ kp) {
  const int gid = blockIdx.x * 256 + threadIdx.x;
  const int frag = gid >> 6, lane = gid & 63;
  const int b = frag >> 11;                 // 64*32 = 2048 frags per batch
  const int rem = frag & 2047;
  const int kg = rem >> 5, ks = rem & 31;
  const int key = kg*32 + (lane & 31);
  const int hi = lane >> 5;
  const float* src = k + ((size_t)(b*LKn) + key)*Dn + ks*16 + hi*8;
  const f32x4 a = *(const f32x4*)src;
  const f32x4 c = *(const f32x4*)(src + 4);
  u16x8 o;
#pragma unroll
  for (int j = 0; j < 4; ++j) { o[j] = f2bfu(a[j]); o[j+4] = f2bfu(c[j]); }
  *(u16x8*)(kp + (size_t)frag*512 + lane*8) = o;
}

// ---- V fp32 [B][LK][D] -> Vp frag-packed bf16: [B][kslice][dg][lane][8] ----
__global__ void conv_vp_kernel(const float* __restrict__ v, unsigned short* __restrict__ vp) {
  __shared__ float vt[16*512];
  const int b = blockIdx.y, kslice = blockIdx.x;
  const float* src = v + ((size_t)(b*LKn) + kslice*16)*Dn;
#pragma unroll
  for (int p = 0; p < 8; ++p) {
    const int idx = p*256 + threadIdx.x;
    *(f32x4*)&vt[idx*4] = *(const f32x4*)(src + (size_t)idx*4);
  }
  __syncthreads();
  unsigned short* dst = vp + ((size_t)(b*128 + kslice)*16)*512;
#pragma unroll
  for (int p = 0; p < 4; ++p) {
    const int slot = p*256 + threadIdx.x;
    const int dg = slot >> 6, lane = slot & 63;
    const int d = dg*32 + (lane & 31);
    const int k0 = (lane >> 5)*8;
    u16x8 o;
#pragma unroll
    for (int j = 0; j < 8; ++j) o[j] = f2bfu(vt[(k0+j)*512 + d]);
    *(u16x8*)(dst + (size_t)dg*512 + lane*8) = o;
  }
}

#define BARRIER_LGKM                                        \
  asm volatile("s_waitcnt lgkmcnt(0)" ::: "memory");        \
  __builtin_amdgcn_s_barrier();                             \
  asm volatile("" ::: "memory");

// ---- flash attention: 32 q-rows/block, 8 waves x 32 keys/iter, rolling reg prefetch ----
__launch_bounds__(512, 2)
__global__ void attn_kernel(const float* __restrict__ q, const unsigned short* __restrict__ kp,
                            const unsigned short* __restrict__ vp,
                            const float* __restrict__ ratio, const float* __restrict__ scalep,
                            const float* __restrict__ maskadd, float* __restrict__ out) {
  __shared__ __align__(16) unsigned short Pl[16*512];   // 16 KiB: [ks(16)][q(32)][hi(2)][8] bf16
  __shared__ __align__(16) float maskl[LKn];            // 8 KiB additive mask for this batch
  __shared__ float redm[8][32];
  __shared__ float reds[8][32];

  const int tid = threadIdx.x;
  const int w = tid >> 6, lane = tid & 63;
  const int qc = lane & 31, hi = lane >> 5;
  const int b = blockIdx.x & 7, qtile = blockIdx.x >> 3;   // XCD-affine batches
  const int qbase = qtile * 32;
  const float c2 = scalep[0] * ratio[b] * 1.4426950408889634f;

  // stage per-batch additive mask into LDS
  *(f32x4*)&maskl[tid*4] = *(const f32x4*)(maskadd + (size_t)b*LKn + tid*4);

  // Q fragments in registers (B-operand: col=q, k=hi*8+j)
  bf16x8 qf[NKS];
  {
    const float* qrow = q + ((size_t)(b*LQn) + qbase + qc)*Dn + hi*8;
#pragma unroll
    for (int ks = 0; ks < 32; ++ks) {
      const f32x4 a = *(const f32x4*)(qrow + ks*16);
      const f32x4 c = *(const f32x4*)(qrow + ks*16 + 4);
      bf16x8 f;
#pragma unroll
      for (int j = 0; j < 4; ++j) { f[j] = (__bf16)a[j]; f[j+4] = (__bf16)c[j]; }
      qf[ks] = f;
    }
  }
  __syncthreads();   // maskl ready (before main loop; one-time vmcnt drain is fine)

  f32x16 o0, o1;
#pragma unroll
  for (int r = 0; r < 16; ++r) { o0[r] = 0.f; o1[r] = 0.f; }
  float m_old = -3.0e38f, lacc = 0.f;

  const char* kpB = (const char*)kp + (size_t)b*(64*NKS)*1024;
  const char* vpB = (const char*)vp + (size_t)b*2048*1024;
  const int loff = lane*16;

  // rolling 8-slot prefetch buffer; preload K frags of iter 0 in consumption order
  // consumption order: KSEQ(i) = (i>>1) + (i&1)*16  (interleaves the two S chains)
  bf16x8 pb[8];
  {
    const char* kf0 = kpB + (size_t)w*32768 + loff;
#pragma unroll
    for (int i = 0; i < 8; ++i)
      pb[i] = *(const bf16x8*)(kf0 + (((i >> 1) + ((i & 1) << 4)) << 10));
  }

  for (int t = 0; t < NT; ++t) {
    const char* kf  = kpB + (size_t)(t*8 + w)*32768 + loff;
    const char* kfn = kpB + (size_t)((((t+1) & 7)*8) + w)*32768 + loff;   // wraps at t=7 (harmless)
    const char* vf  = vpB + ((size_t)(t*256) + w*2)*1024 + loff;

    // mask values for this wave's 32 keys (broadcast ds_reads, issued early)
    f32x4 m4[4];
#pragma unroll
    for (int g = 0; g < 4; ++g)
      m4[g] = *(const f32x4*)&maskl[t*256 + w*32 + g*8 + hi*4];

    // ---- QK^T: S[key][q], two independent chains, rolling K->V prefetch ----
    f32x16 S0, S1;
#pragma unroll
    for (int r = 0; r < 16; ++r) { S0[r] = 0.f; S1[r] = 0.f; }
#pragma unroll
    for (int i = 0; i < 32; ++i) {
      const int ks = (i >> 1) + ((i & 1) << 4);
      if (i & 1) S1 = __builtin_amdgcn_mfma_f32_32x32x16_bf16(pb[i & 7], qf[ks], S1, 0, 0, 0);
      else       S0 = __builtin_amdgcn_mfma_f32_32x32x16_bf16(pb[i & 7], qf[ks], S0, 0, 0, 0);
      if (i < 24) {
        const int n = i + 8;
        pb[i & 7] = *(const bf16x8*)(kf + (((n >> 1) + ((n & 1) << 4)) << 10));
      } else {
        const int j = i - 24;                       // first 8 V frags of this iter
        pb[i & 7] = *(const bf16x8*)(vf + (size_t)(j >> 1)*16384 + (j & 1)*1024);
      }
    }

    // ---- softmax ----
    float sl[16];
    float vmax = -3.0e38f;
#pragma unroll
    for (int r = 0; r < 16; ++r) {
      sl[r] = (S0[r] + S1[r])*c2 + m4[r >> 2][r & 3];
      vmax = fmaxf(vmax, sl[r]);
    }
    vmax = fmaxf(vmax, __shfl_xor(vmax, 32));
    if (lane < 32) redm[w][lane] = vmax;
    BARRIER_LGKM;                                   // barrier A (no vmcnt drain)

    float mt = redm[0][qc];
#pragma unroll
    for (int w2 = 1; w2 < 8; ++w2) mt = fmaxf(mt, redm[w2][qc]);
    const float m_new = fmaxf(m_old, mt);
    const float fac = exp2f(m_old - m_new);
    m_old = m_new;

    float ps = 0.f;
    unsigned int pw[8];
#pragma unroll
    for (int r = 0; r < 16; r += 2) {
      const float p0 = exp2f(sl[r]   - m_new);
      const float p1 = exp2f(sl[r+1] - m_new);
      ps += p0 + p1;
      pw[r >> 1] = (unsigned int)f2bfu(p0) | ((unsigned int)f2bfu(p1) << 16);
    }
    {
      char* pbp = (char*)Pl + (w*2)*1024 + qc*32 + hi*8;
      *(unsigned long long*)(pbp)        = (unsigned long long)pw[0] | ((unsigned long long)pw[1] << 32);
      *(unsigned long long*)(pbp + 16)   = (unsigned long long)pw[2] | ((unsigned long long)pw[3] << 32);
      *(unsigned long long*)(pbp + 1024) = (unsigned long long)pw[4] | ((unsigned long long)pw[5] << 32);
      *(unsigned long long*)(pbp + 1040) = (unsigned long long)pw[6] | ((unsigned long long)pw[7] << 32);
    }
    ps += __shfl_xor(ps, 32);
    if (lane < 32) reds[w][lane] = ps;
    BARRIER_LGKM;                                   // barrier B (no vmcnt drain)

    float lsum = reds[0][qc];
#pragma unroll
    for (int w2 = 1; w2 < 8; ++w2) lsum += reds[w2][qc];
    lacc = lacc*fac + lsum;
#pragma unroll
    for (int r = 0; r < 16; ++r) { o0[r] *= fac; o1[r] *= fac; }

    // ---- PV: wave owns d-groups w*2, w*2+1; rolling V refills, tail preloads next K ----
    const char* prc = (const char*)Pl + qc*32 + hi*16;
    const int tn = (t + 1 < NT) ? 1 : 0;
#pragma unroll
    for (int ks2 = 0; ks2 < 16; ++ks2) {
      const bf16x8 pf = *(const bf16x8*)(prc + ks2*1024);
      o0 = __builtin_amdgcn_mfma_f32_32x32x16_bf16(pb[(2*ks2) & 7],     pf, o0, 0, 0, 0);
      o1 = __builtin_amdgcn_mfma_f32_32x32x16_bf16(pb[(2*ks2 + 1) & 7], pf, o1, 0, 0, 0);
      if (ks2 < 12) {
        const int j0 = 2*ks2 + 8, j1 = 2*ks2 + 9;
        pb[(2*ks2) & 7]     = *(const bf16x8*)(vf + (size_t)(j0 >> 1)*16384 + (j0 & 1)*1024);
        pb[(2*ks2 + 1) & 7] = *(const bf16x8*)(vf + (size_t)(j1 >> 1)*16384 + (j1 & 1)*1024);
      } else if (tn) {
        const int i0 = 2*(ks2 - 12), i1 = i0 + 1;
        pb[(2*ks2) & 7]     = *(const bf16x8*)(kfn + (((i0 >> 1) + ((i0 & 1) << 4)) << 10));
        pb[(2*ks2 + 1) & 7] = *(const bf16x8*)(kfn + (((i1 >> 1) + ((i1 & 1) << 4)) << 10));
      }
    }
  }

  // epilogue: out[q][d] = O^T[d][q] / l   (C row = (r&3)+8*(r>>2)+4*hi)
  const float linv = 1.0f / lacc;
  float* ob = out + ((size_t)(b*LQn) + qbase + qc)*Dn;
#pragma unroll
  for (int i = 0; i < 2; ++i) {
    const int dgb = (w*2 + i)*32;
#pragma unroll
    for (int rq = 0; rq < 4; ++rq) {
      f32x4 ov;
#pragma unroll
      for (int c = 0; c < 4; ++c) ov[c] = (i ? o1[rq*4 + c] : o0[rq*4 + c]) * linv;
      *(f32x4*)(ob + dgb + rq*8 + hi*4) = ov;
    }
  }
}

extern "C" void kernel_launch(void* const* d_in, const int* in_sizes, int n_in,
                              void* d_out, int out_size, void* d_ws, size_t ws_size,
                              hipStream_t stream) {
  const float* q      = (const float*)d_in[0];
  const float* k      = (const float*)d_in[1];
  const float* v      = (const float*)d_in[2];
  const float* ratio  = (const float*)d_in[3];
  const float* scalep = (const float*)d_in[4];
  const void*  mask   = d_in[5];
  float* out = (float*)d_out;
  char* ws = (char*)d_ws;

  if (ws_size < WS_REQ) return;

  float* maskadd      = (float*)(ws + WS_MASK_OFF);
  unsigned short* kpk = (unsigned short*)(ws + WS_KP_OFF);
  unsigned short* vpk = (unsigned short*)(ws + WS_VP_OFF);

  hipLaunchKernelGGL(mask_prep_kernel, dim3(1), dim3(1024), 0, stream, mask, maskadd);
  hipLaunchKernelGGL(conv_kp_kernel, dim3(Bn*64*NKS*64/256), dim3(256), 0, stream, k, kpk);
  hipLaunchKernelGGL(conv_vp_kernel, dim3(128, Bn), dim3(256), 0, stream, v, vpk);
  hipLaunchKernelGGL(attn_kernel, dim3(Bn*(LQn/32)), dim3(512), 0, stream,
                     q, kpk, vpk, ratio, scalep, maskadd, out);
}

// Round 5
// 121.736 us; speedup vs baseline: 1.9596x; 1.6689x over previous
//
#include <hip/hip_runtime.h>
#include <stdint.h>

#define Bn  8
#define LQn 2048
#define LKn 2048
#define Dn  512
#define NT  8           // 2048 keys / 256 per iter

using f32x4  = __attribute__((ext_vector_type(4)))  float;
using f32x16 = __attribute__((ext_vector_type(16))) float;
using bf16x8 = __attribute__((ext_vector_type(8)))  __bf16;
using u16x8  = __attribute__((ext_vector_type(8)))  unsigned short;

// ws layout
#define WS_MASK_OFF 256
#define WS_KP_OFF   (WS_MASK_OFF + Bn*LKn*4)                 // K pack: [B][64 kg][32 ks][64 lane][8] bf16
#define KP_BYTES    ((size_t)Bn*64*32*1024)
#define WS_VP_OFF   (WS_KP_OFF + KP_BYTES)                   // V pack: [B][128 kslice][16 dg][64 lane][8] bf16
#define VP_BYTES    ((size_t)Bn*128*16*1024)
#define WS_REQ      ((size_t)WS_VP_OFF + VP_BYTES)

union BFU { __bf16 h; unsigned short u; };
static __device__ __forceinline__ unsigned short f2bfu(float x) { BFU t; t.h = (__bf16)x; return t.u; }

// ---- mask dtype detect + additive bias build: maskadd = masked ? -1e30 : 0 ----
__global__ void mask_prep_kernel(const void* __restrict__ mraw, float* __restrict__ maskadd) {
  __shared__ int sBig, sOff;
  const int tid = threadIdx.x;
  if (tid == 0) { sBig = 0; sOff = 0; }
  __syncthreads();
  const unsigned char* mb = (const unsigned char*)mraw;
  int big = 0, off = 0;
  for (int i = tid; i < Bn*LKn; i += blockDim.x) {
    unsigned char v = mb[i];
    big |= (v > 1) ? 1 : 0;
    off |= (((i & 3) != 0) && v != 0) ? 1 : 0;
  }
  if (big) atomicOr(&sBig, 1);
  if (off) atomicOr(&sOff, 1);
  __syncthreads();
  const int f = sBig ? 2 : (sOff ? 1 : 0);
  for (int i = tid; i < Bn*LKn; i += blockDim.x) {
    bool m;
    if (f == 2)      m = ((const float*)mraw)[i] != 0.0f;
    else if (f == 1) m = mb[i] != 0;
    else             m = ((const int*)mraw)[i] != 0;
    maskadd[i] = m ? -1e30f : 0.0f;
  }
}

// ---- K fp32 [B][LK][D] -> Kp frag-packed bf16 ----
__global__ void conv_kp_kernel(const float* __restrict__ k, unsigned short* __restrict__ kp) {
  const int gid = blockIdx.x * 256 + threadIdx.x;
  const int frag = gid >> 6, lane = gid & 63;
  const int b = frag >> 11;                 // 64*32 = 2048 frags per batch
  const int rem = frag & 2047;
  const int kg = rem >> 5, ks = rem & 31;
  const int key = kg*32 + (lane & 31);
  const int hi = lane >> 5;
  const float* src = k + ((size_t)(b*LKn) + key)*Dn + ks*16 + hi*8;
  const f32x4 a = *(const f32x4*)src;
  const f32x4 c = *(const f32x4*)(src + 4);
  u16x8 o;
#pragma unroll
  for (int j = 0; j < 4; ++j) { o[j] = f2bfu(a[j]); o[j+4] = f2bfu(c[j]); }
  *(u16x8*)(kp + (size_t)frag*512 + lane*8) = o;
}

// ---- V fp32 [B][LK][D] -> Vp frag-packed bf16: [B][kslice][dg][lane][8] ----
__global__ void conv_vp_kernel(const float* __restrict__ v, unsigned short* __restrict__ vp) {
  __shared__ float vt[16*512];
  const int b = blockIdx.y, kslice = blockIdx.x;
  const float* src = v + ((size_t)(b*LKn) + kslice*16)*Dn;
#pragma unroll
  for (int p = 0; p < 8; ++p) {
    const int idx = p*256 + threadIdx.x;
    *(f32x4*)&vt[idx*4] = *(const f32x4*)(src + (size_t)idx*4);
  }
  __syncthreads();
  unsigned short* dst = vp + ((size_t)(b*128 + kslice)*16)*512;
#pragma unroll
  for (int p = 0; p < 4; ++p) {
    const int slot = p*256 + threadIdx.x;
    const int dg = slot >> 6, lane = slot & 63;
    const int d = dg*32 + (lane & 31);
    const int k0 = (lane >> 5)*8;
    u16x8 o;
#pragma unroll
    for (int j = 0; j < 8; ++j) o[j] = f2bfu(vt[(k0+j)*512 + d]);
    *(u16x8*)(dst + (size_t)dg*512 + lane*8) = o;
  }
}

#define BARRIER_LGKM                                        \
  asm volatile("s_waitcnt lgkmcnt(0)" ::: "memory");        \
  __builtin_amdgcn_s_barrier();                             \
  asm volatile("" ::: "memory");

// ---- flash attention: QBLK=64 (Q in LDS), 8 waves x 32 keys/iter, 16-deep rolling prefetch ----
__launch_bounds__(512, 2)
__global__ void attn_kernel(const float* __restrict__ q, const unsigned short* __restrict__ kp,
                            const unsigned short* __restrict__ vp,
                            const float* __restrict__ ratio, const float* __restrict__ scalep,
                            const float* __restrict__ maskadd, float* __restrict__ out) {
  __shared__ __align__(16) unsigned short Ql[2*32*512];   // 64 KiB: [qg][ks][qc][hi][8] bf16
  __shared__ __align__(16) unsigned short Pl[2*16*512];   // 32 KiB: [qg][ks][qc][hi][8] bf16
  __shared__ __align__(16) float maskl[LKn];              // 8 KiB
  __shared__ float redm[8][64];
  __shared__ float reds[8][64];

  const int tid = threadIdx.x;
  const int w = tid >> 6, lane = tid & 63;
  const int qc = lane & 31, hi = lane >> 5;
  const int b = blockIdx.x & 7, qtile = blockIdx.x >> 3;   // XCD-affine batches
  const int qbase = qtile * 64;
  const float c2 = scalep[0] * ratio[b] * 1.4426950408889634f;  // log2-domain scale

  // stage per-batch additive mask
  *(f32x4*)&maskl[tid*4] = *(const f32x4*)(maskadd + (size_t)b*LKn + tid*4);

  // stage Q -> LDS bf16 frag layout (4096 16B-chunks, 8 per thread)
#pragma unroll
  for (int cc = 0; cc < 8; ++cc) {
    const int idx = cc*512 + tid;
    const int hi2 = idx & 1, qc2 = (idx >> 1) & 31, ks2 = (idx >> 6) & 31, qg2 = idx >> 11;
    const float* src = q + ((size_t)(b*LQn) + qbase + qg2*32 + qc2)*Dn + ks2*16 + hi2*8;
    const f32x4 a = *(const f32x4*)src;
    const f32x4 bb = *(const f32x4*)(src + 4);
    u16x8 o;
#pragma unroll
    for (int j = 0; j < 4; ++j) { o[j] = f2bfu(a[j]); o[j+4] = f2bfu(bb[j]); }
    *(u16x8*)((char*)Ql + qg2*32768 + ks2*1024 + qc2*32 + hi2*16) = o;
  }
  __syncthreads();   // one-time full drain (prologue only)

  f32x16 o00, o01, o10, o11;   // [qg][dg]; C col = q, rows = d
#pragma unroll
  for (int r = 0; r < 16; ++r) { o00[r]=0.f; o01[r]=0.f; o10[r]=0.f; o11[r]=0.f; }
  float m0 = -3.0e38f, m1 = -3.0e38f, l0 = 0.f, l1 = 0.f;

  const char* kpB = (const char*)kp + (size_t)b*2048*1024;
  const char* vpB = (const char*)vp + (size_t)b*2048*1024;
  const int loff = lane*16;
  const char* Qlb = (const char*)Ql + qc*32 + hi*16;
  const char* prc = (const char*)Pl + qc*32 + hi*16;

  // 16-slot rolling prefetch ring; preload K frags 0..15 of iter 0
  bf16x8 pb[16];
  {
    const char* kf0 = kpB + (size_t)w*32768 + loff;
#pragma unroll
    for (int i = 0; i < 16; ++i) pb[i] = *(const bf16x8*)(kf0 + i*1024);
  }

  for (int t = 0; t < NT; ++t) {
    const char* kf  = kpB + (size_t)(t*8 + w)*32768 + loff;
    const char* kfn = kpB + (size_t)((t+1 < NT ? t+1 : 0)*8 + w)*32768 + loff;
    const char* vf  = vpB + ((size_t)(t*16)*16 + w*2)*1024 + loff;
    const int tn = (t + 1 < NT) ? 1 : 0;

    // mask for this wave's 32 keys (rows r of S; key = (r&3)+8*(r>>2)+4*hi)
    f32x4 m4[4];
#pragma unroll
    for (int g = 0; g < 4; ++g)
      m4[g] = *(const f32x4*)&maskl[t*256 + w*32 + g*8 + hi*4];

    // ---- QK^T: S[32key x 32q] x 2 q-groups; rolling K->V refills ----
    f32x16 S0, S1;
#pragma unroll
    for (int r = 0; r < 16; ++r) { S0[r] = 0.f; S1[r] = 0.f; }
    __builtin_amdgcn_s_setprio(1);
#pragma unroll
    for (int i = 0; i < 32; ++i) {
      const bf16x8 kk = pb[i & 15];
      const bf16x8 q0 = *(const bf16x8*)(Qlb + i*1024);
      const bf16x8 q1 = *(const bf16x8*)(Qlb + 32768 + i*1024);
      S0 = __builtin_amdgcn_mfma_f32_32x32x16_bf16(kk, q0, S0, 0, 0, 0);
      S1 = __builtin_amdgcn_mfma_f32_32x32x16_bf16(kk, q1, S1, 0, 0, 0);
      if (i < 16) {
        pb[i & 15] = *(const bf16x8*)(kf + (i+16)*1024);
      } else {
        const int j = i - 16;                       // first 16 V frags of this iter
        pb[i & 15] = *(const bf16x8*)(vf + (size_t)(j >> 1)*16384 + (j & 1)*1024);
      }
    }
    __builtin_amdgcn_s_setprio(0);

    // ---- softmax (both q-groups) ----
    float sl0[16], sl1[16];
    float vx0 = -3.0e38f, vx1 = -3.0e38f;
#pragma unroll
    for (int r = 0; r < 16; ++r) {
      const float mr = m4[r >> 2][r & 3];
      sl0[r] = S0[r]*c2 + mr; vx0 = fmaxf(vx0, sl0[r]);
      sl1[r] = S1[r]*c2 + mr; vx1 = fmaxf(vx1, sl1[r]);
    }
    vx0 = fmaxf(vx0, __shfl_xor(vx0, 32));
    vx1 = fmaxf(vx1, __shfl_xor(vx1, 32));
    if (lane < 32) { redm[w][qc] = vx0; redm[w][32 + qc] = vx1; }
    BARRIER_LGKM;                                   // barrier A (no vmcnt drain)

    float mt0 = redm[0][qc], mt1 = redm[0][32 + qc];
#pragma unroll
    for (int w2 = 1; w2 < 8; ++w2) {
      mt0 = fmaxf(mt0, redm[w2][qc]);
      mt1 = fmaxf(mt1, redm[w2][32 + qc]);
    }
    const float mn0 = fmaxf(m0, mt0), mn1 = fmaxf(m1, mt1);
    const float fac0 = exp2f(m0 - mn0), fac1 = exp2f(m1 - mn1);
    m0 = mn0; m1 = mn1;

    float ps0 = 0.f, ps1 = 0.f;
    {
      char* pw0p = (char*)Pl + (w*2)*1024 + qc*32 + hi*8;
#pragma unroll
      for (int g = 0; g < 4; ++g) {
        const int off = (g & 1)*16 + (g >> 1)*1024;
        float p0 = exp2f(sl0[g*4+0] - mn0), p1 = exp2f(sl0[g*4+1] - mn0);
        float p2 = exp2f(sl0[g*4+2] - mn0), p3 = exp2f(sl0[g*4+3] - mn0);
        ps0 += (p0 + p1) + (p2 + p3);
        unsigned long long u0 = (unsigned long long)((unsigned int)f2bfu(p0) | ((unsigned int)f2bfu(p1) << 16))
                              | ((unsigned long long)((unsigned int)f2bfu(p2) | ((unsigned int)f2bfu(p3) << 16)) << 32);
        *(unsigned long long*)(pw0p + off) = u0;
        p0 = exp2f(sl1[g*4+0] - mn1); p1 = exp2f(sl1[g*4+1] - mn1);
        p2 = exp2f(sl1[g*4+2] - mn1); p3 = exp2f(sl1[g*4+3] - mn1);
        ps1 += (p0 + p1) + (p2 + p3);
        unsigned long long u1 = (unsigned long long)((unsigned int)f2bfu(p0) | ((unsigned int)f2bfu(p1) << 16))
                              | ((unsigned long long)((unsigned int)f2bfu(p2) | ((unsigned int)f2bfu(p3) << 16)) << 32);
        *(unsigned long long*)(pw0p + 16384 + off) = u1;
      }
    }
    ps0 += __shfl_xor(ps0, 32);
    ps1 += __shfl_xor(ps1, 32);
    if (lane < 32) { reds[w][qc] = ps0; reds[w][32 + qc] = ps1; }
    BARRIER_LGKM;                                   // barrier B (no vmcnt drain)

    float ls0 = reds[0][qc], ls1 = reds[0][32 + qc];
#pragma unroll
    for (int w2 = 1; w2 < 8; ++w2) { ls0 += reds[w2][qc]; ls1 += reds[w2][32 + qc]; }
    l0 = l0*fac0 + ls0;
    l1 = l1*fac1 + ls1;
#pragma unroll
    for (int r = 0; r < 16; ++r) {
      o00[r] *= fac0; o01[r] *= fac0;
      o10[r] *= fac1; o11[r] *= fac1;
    }

    // ---- PV: wave owns 64 d-cols x 64 q; rolling V refills, tail preloads next-iter K ----
    __builtin_amdgcn_s_setprio(1);
#pragma unroll
    for (int ks2 = 0; ks2 < 16; ++ks2) {
      const bf16x8 pf0 = *(const bf16x8*)(prc + ks2*1024);
      const bf16x8 pf1 = *(const bf16x8*)(prc + 16384 + ks2*1024);
      const bf16x8 v0 = pb[(2*ks2) & 15];
      const bf16x8 v1 = pb[(2*ks2 + 1) & 15];
      o00 = __builtin_amdgcn_mfma_f32_32x32x16_bf16(v0, pf0, o00, 0, 0, 0);
      o10 = __builtin_amdgcn_mfma_f32_32x32x16_bf16(v0, pf1, o10, 0, 0, 0);
      o01 = __builtin_amdgcn_mfma_f32_32x32x16_bf16(v1, pf0, o01, 0, 0, 0);
      o11 = __builtin_amdgcn_mfma_f32_32x32x16_bf16(v1, pf1, o11, 0, 0, 0);
      const int j0 = 2*ks2, j1 = 2*ks2 + 1;
      if (j0 < 16) {
        pb[j0 & 15] = *(const bf16x8*)(vf + (size_t)((j0+16) >> 1)*16384 + ((j0+16) & 1)*1024);
        pb[j1 & 15] = *(const bf16x8*)(vf + (size_t)((j1+16) >> 1)*16384 + ((j1+16) & 1)*1024);
      } else if (tn) {
        pb[j0 & 15] = *(const bf16x8*)(kfn + (j0-16)*1024);
        pb[j1 & 15] = *(const bf16x8*)(kfn + (j1-16)*1024);
      }
    }
    __builtin_amdgcn_s_setprio(0);
  }

  // epilogue: out[q][d] = O^T[d][q] / l   (C row = (r&3)+8*(r>>2)+4*hi)
  const float li0 = 1.0f / l0, li1 = 1.0f / l1;
  float* ob0 = out + ((size_t)(b*LQn) + qbase + qc)*Dn + w*64;
  float* ob1 = ob0 + (size_t)32*Dn;
#pragma unroll
  for (int dg = 0; dg < 2; ++dg) {
#pragma unroll
    for (int rq = 0; rq < 4; ++rq) {
      f32x4 ov0, ov1;
#pragma unroll
      for (int c = 0; c < 4; ++c) {
        if (dg == 0) { ov0[c] = o00[rq*4 + c]*li0; ov1[c] = o10[rq*4 + c]*li1; }
        else         { ov0[c] = o01[rq*4 + c]*li0; ov1[c] = o11[rq*4 + c]*li1; }
      }
      *(f32x4*)(ob0 + dg*32 + rq*8 + hi*4) = ov0;
      *(f32x4*)(ob1 + dg*32 + rq*8 + hi*4) = ov1;
    }
  }
}

extern "C" void kernel_launch(void* const* d_in, const int* in_sizes, int n_in,
                              void* d_out, int out_size, void* d_ws, size_t ws_size,
                              hipStream_t stream) {
  const float* q      = (const float*)d_in[0];
  const float* k      = (const float*)d_in[1];
  const float* v      = (const float*)d_in[2];
  const float* ratio  = (const float*)d_in[3];
  const float* scalep = (const float*)d_in[4];
  const void*  mask   = d_in[5];
  float* out = (float*)d_out;
  char* ws = (char*)d_ws;

  if (ws_size < WS_REQ) return;

  float* maskadd      = (float*)(ws + WS_MASK_OFF);
  unsigned short* kpk = (unsigned short*)(ws + WS_KP_OFF);
  unsigned short* vpk = (unsigned short*)(ws + WS_VP_OFF);

  hipLaunchKernelGGL(mask_prep_kernel, dim3(1), dim3(1024), 0, stream, mask, maskadd);
  hipLaunchKernelGGL(conv_kp_kernel, dim3(Bn*64*32*64/256), dim3(256), 0, stream, k, kpk);
  hipLaunchKernelGGL(conv_vp_kernel, dim3(128, Bn), dim3(256), 0, stream, v, vpk);
  hipLaunchKernelGGL(attn_kernel, dim3(Bn*(LQn/64)), dim3(512), 0, stream,
                     q, kpk, vpk, ratio, scalep, maskadd, out);
}